// Round 1
// baseline (200.151 us; speedup 1.0000x reference)
//
#include <hip/hip_runtime.h>
#include <stdint.h>

#define BATCH 32
#define IMG 512
#define CH 3
#define GOUT 64
#define ROWB (IMG*CH)   // 1536 floats per image row
#define GP   ((size_t)BATCH*CH*GOUT*IMG)   // one K-split partial of planar g

typedef __attribute__((ext_vector_type(8))) short  short8;   // 8 bf16 = 4 VGPRs
typedef __attribute__((ext_vector_type(4))) float  floatx4;  // MFMA 16x16 acc

__device__ __forceinline__ unsigned short f2bf(float x) {
    unsigned u = __builtin_bit_cast(unsigned, x);
    u += 0x7FFFu + ((u >> 16) & 1u);
    return (unsigned short)(u >> 16);
}

// ---------------------------------------------------------------------------
// Kernel 1: Gaussian filterbank masks, TRANSPOSED bf16: AyT[b][H][h],
// AxT[b][W][w] (k-contiguous). One wave per (b, axis, r). (unchanged, verified)
// ---------------------------------------------------------------------------
__global__ __launch_bounds__(64) void mask_kernel(const float* __restrict__ tp,
                                                  unsigned short* __restrict__ AyT,
                                                  unsigned short* __restrict__ AxT) {
    int blk  = blockIdx.x;
    int r    = blk & 63;
    int axis = (blk >> 6) & 1;
    int b    = blk >> 7;

    const float* p = tp + b*6 + (axis ? 3 : 0);
    float u = p[0], s = p[1], d = p[2];
    float centre = u + (float)r * d;
    float inv_s  = 1.0f / s;

    int lane = threadIdx.x;
    float e[8];
    float sum = 0.0f;
    #pragma unroll
    for (int i = 0; i < 8; ++i) {
        float z = ((float)(i*64 + lane) - centre) * inv_s;
        e[i] = __expf(-0.5f * z * z);
        sum += e[i];
    }
    #pragma unroll
    for (int m = 1; m < 64; m <<= 1)
        sum += __shfl_xor(sum, m, 64);
    float inv_sum = 1.0f / (sum + 1e-8f);

    unsigned short* dst = (axis ? AxT : AyT) + ((size_t)b*GOUT + r) * IMG;
    #pragma unroll
    for (int i = 0; i < 8; ++i)
        dst[i*64 + lane] = f2bf(e[i] * inv_sum);
}

// ---------------------------------------------------------------------------
// Kernel 2: gP[part][b][c][H][w] = sum_{h in part} Ay[b,h,H]*img[b,h,w,c]
// Round-6 redesign: NO LDS, NO barriers. img has zero inter-block reuse, so
// B-fragments (8 h-contiguous floats at fixed wc) load DIRECTLY from global:
// 16 scalar dwords/lane/chunk; a wave's 64 lanes still cover 4 rows x 64 B
// contiguous, and the 4 waves complete each 256-B row segment -> full lines.
// Ay A-fragments load straight from L2-resident AyT (bf16, k-contiguous 16 B).
// Removes: 4-way-conflicted ds_read_b32 x16, async staging, 2 syncthreads
// per chunk, 25.6 KB LDS. Pure streaming MFMA, HBM-bound.
// ---------------------------------------------------------------------------
__global__ __launch_bounds__(256, 4) void stage1_kernel(const float* __restrict__ img,
                                                        const unsigned short* __restrict__ AyT,
                                                        float* __restrict__ gP) {
    int part = blockIdx.x & 1;
    int bt   = blockIdx.x >> 1;
    int tile = bt % 24;
    int b    = bt / 24;
    int wc0  = tile * 64;
    int tid  = threadIdx.x;
    int wave = tid >> 6;
    int lane = tid & 63;
    int n16  = lane & 15;
    int q    = lane >> 4;

    floatx4 acc[4];
    #pragma unroll
    for (int mt = 0; mt < 4; ++mt) acc[mt] = (floatx4){0.f, 0.f, 0.f, 0.f};

    // per-lane column pointer: this lane's wc within the 64-wide tile
    const float*          imb = img + (size_t)b * IMG * ROWB + wc0 + wave*16 + n16;
    const unsigned short* ayb = AyT + (size_t)b * GOUT * IMG;

    // K-loop: 8 chunks of 32 h. MFMA k = q*8 + j  ->  h = h0 + q*8 + j.
    for (int h0 = part*256; h0 < part*256 + 256; h0 += 32) {
        int hk = h0 + q*8;
        const float* ip = imb + (size_t)hk * ROWB;
        short8 bf;
        #pragma unroll
        for (int j = 0; j < 8; ++j)
            bf[j] = (short)f2bf(ip[(size_t)j * ROWB]);
        #pragma unroll
        for (int mt = 0; mt < 4; ++mt) {
            short8 af = *(const short8*)(ayb + (size_t)(mt*16 + n16) * IMG + hk);
            acc[mt] = __builtin_amdgcn_mfma_f32_16x16x32_bf16(af, bf, acc[mt], 0, 0, 0);
        }
    }

    // Epilogue: D col = lane&15 -> wc, row = q*4+reg -> H (verified r4/r5).
    int wc = wc0 + wave*16 + n16;
    int c = wc % 3, w = wc / 3;
    float* gb = gP + (size_t)part * GP + ((size_t)(b*CH + c) * GOUT) * IMG + w;
    #pragma unroll
    for (int mt = 0; mt < 4; ++mt)
        #pragma unroll
        for (int reg = 0; reg < 4; ++reg)
            gb[(size_t)(mt*16 + q*4 + reg) * IMG] = acc[mt][reg];
}

// ---------------------------------------------------------------------------
// Kernel 3: out[b,H,W,c] = sum_w (g0+g1)[b,c,H,w] * Ax[b,w,W]
// Round-6 redesign: split over H-quadrants (grid b*c*4 = 384), each block
// runs full K=512 in ONE accumulation chain and stores directly.
// No atomics, no d_out memset, one fewer dispatch. Each wave: 16H x 16W tile.
// ---------------------------------------------------------------------------
__global__ __launch_bounds__(256) void stage2_kernel(const float* __restrict__ gP,
                                                     const unsigned short* __restrict__ AxT,
                                                     float* __restrict__ out) {
    int blk  = blockIdx.x;
    int hq   = blk & 3;          // H-quadrant (16 rows)
    int bc   = blk >> 2;
    int c    = bc % 3;
    int b    = bc / 3;
    int tid  = threadIdx.x;
    int wave = tid >> 6;         // owns W-tile wave*16..+15
    int lane = tid & 63;
    int n16  = lane & 15;
    int q    = lane >> 4;

    floatx4 acc = (floatx4){0.f, 0.f, 0.f, 0.f};

    // A row for this lane: g[b,c][H = hq*16 + n16][*]
    const float*          ga  = gP  + ((size_t)(b*CH + c) * GOUT + hq*16 + n16) * IMG;
    // B rows: AxT[b][W = wave*16 + n16][*]  (k-contiguous bf16)
    const unsigned short* axb = AxT + ((size_t)b*GOUT + wave*16 + n16) * IMG;

    #pragma unroll 4
    for (int cc = 0; cc < 16; ++cc) {
        int w0 = cc*32 + q*8;
        float4 a0 = *(const float4*)(ga + w0);
        float4 a1 = *(const float4*)(ga + w0 + 4);
        float4 b0 = *(const float4*)(ga + GP + w0);
        float4 b1 = *(const float4*)(ga + GP + w0 + 4);
        short8 af;
        af[0] = (short)f2bf(a0.x + b0.x); af[1] = (short)f2bf(a0.y + b0.y);
        af[2] = (short)f2bf(a0.z + b0.z); af[3] = (short)f2bf(a0.w + b0.w);
        af[4] = (short)f2bf(a1.x + b1.x); af[5] = (short)f2bf(a1.y + b1.y);
        af[6] = (short)f2bf(a1.z + b1.z); af[7] = (short)f2bf(a1.w + b1.w);

        short8 bf = *(const short8*)(axb + w0);
        acc = __builtin_amdgcn_mfma_f32_16x16x32_bf16(af, bf, acc, 0, 0, 0);
    }

    // D: col = lane&15 -> W offset, row = q*4+reg -> H offset. Disjoint, plain stores.
    float* ob = out + (((size_t)b*GOUT + hq*16) * GOUT + wave*16 + n16) * CH + c;
    #pragma unroll
    for (int reg = 0; reg < 4; ++reg)
        ob[(size_t)(q*4 + reg) * GOUT * CH] = acc[reg];
}

// ---------------------------------------------------------------------------
// Workspace: AyT 2 MB | AxT 2 MB | gP 2 x 12.6 MB  (~29 MB).
// ---------------------------------------------------------------------------
extern "C" void kernel_launch(void* const* d_in, const int* in_sizes, int n_in,
                              void* d_out, int out_size, void* d_ws, size_t ws_size,
                              hipStream_t stream) {
    const float* img = (const float*)d_in[0];
    const float* tp  = (const float*)d_in[1];
    float* out = (float*)d_out;

    unsigned short* AyT = (unsigned short*)d_ws;
    unsigned short* AxT = AyT + (size_t)BATCH * GOUT * IMG;
    float*          gPp = (float*)(AxT + (size_t)BATCH * GOUT * IMG);

    mask_kernel  <<<BATCH * 2 * GOUT,  64, 0, stream>>>(tp, AyT, AxT);
    stage1_kernel<<<BATCH * 24 * 2,   256, 0, stream>>>(img, AyT, gPp);
    stage2_kernel<<<BATCH * CH * 4,   256, 0, stream>>>(gPp, AxT, out);
}

// Round 2
// 189.965 us; speedup vs baseline: 1.0536x; 1.0536x over previous
//
#include <hip/hip_runtime.h>
#include <stdint.h>

#define BATCH 32
#define IMG 512
#define CH 3
#define GOUT 64
#define ROWB (IMG*CH)   // 1536 floats per image row
#define GP   ((size_t)BATCH*CH*GOUT*IMG)   // one K-split partial of planar g

typedef __attribute__((ext_vector_type(8))) short  short8;   // 8 bf16 = 4 VGPRs
typedef __attribute__((ext_vector_type(4))) float  floatx4;  // MFMA 16x16 acc
typedef __attribute__((ext_vector_type(4))) float  floatv4;  // indexable float4

__device__ __forceinline__ unsigned short f2bf(float x) {
    unsigned u = __builtin_bit_cast(unsigned, x);
    u += 0x7FFFu + ((u >> 16) & 1u);
    return (unsigned short)(u >> 16);
}

// ---------------------------------------------------------------------------
// Kernel 1: Gaussian filterbank masks, TRANSPOSED bf16: AyT[b][H][h],
// AxT[b][W][w] (k-contiguous). One wave per (b, axis, r). (unchanged, verified)
// ---------------------------------------------------------------------------
__global__ __launch_bounds__(64) void mask_kernel(const float* __restrict__ tp,
                                                  unsigned short* __restrict__ AyT,
                                                  unsigned short* __restrict__ AxT) {
    int blk  = blockIdx.x;
    int r    = blk & 63;
    int axis = (blk >> 6) & 1;
    int b    = blk >> 7;

    const float* p = tp + b*6 + (axis ? 3 : 0);
    float u = p[0], s = p[1], d = p[2];
    float centre = u + (float)r * d;
    float inv_s  = 1.0f / s;

    int lane = threadIdx.x;
    float e[8];
    float sum = 0.0f;
    #pragma unroll
    for (int i = 0; i < 8; ++i) {
        float z = ((float)(i*64 + lane) - centre) * inv_s;
        e[i] = __expf(-0.5f * z * z);
        sum += e[i];
    }
    #pragma unroll
    for (int m = 1; m < 64; m <<= 1)
        sum += __shfl_xor(sum, m, 64);
    float inv_sum = 1.0f / (sum + 1e-8f);

    unsigned short* dst = (axis ? AxT : AyT) + ((size_t)b*GOUT + r) * IMG;
    #pragma unroll
    for (int i = 0; i < 8; ++i)
        dst[i*64 + lane] = f2bf(e[i] * inv_sum);
}

// ---------------------------------------------------------------------------
// Kernel 2: gP[part][b][c][H][w] = sum_{h in part} Ay[b,h,H]*img[b,h,w,c]
// Round-7: LDS transpose tile with granule-XOR swizzle.
//   Bs row = wc (64 rows x 64 h floats, stride 64 = 16B-aligned).
//   16B h-granule hg of row wc stored at position hg ^ (wc>>2).
//   - staging: coalesced dwordx4 global reads (4x256B rows/instr),
//     scatter ds_write_b32: banks = 2 lanes/bank (free).
//   - column reads: ds_read_b128 x2 per 32h, 8 granule-groups x 8 lanes
//     = wave64 b128 optimum (conflict-free).
//   T14 split: chunk t+1 global loads issued before chunk t compute.
//   6 blocks/CU (16.4 KB LDS) for cross-block latency overlap.
// ---------------------------------------------------------------------------
__global__ __launch_bounds__(256, 6) void stage1_kernel(const float* __restrict__ img,
                                                        const unsigned short* __restrict__ AyT,
                                                        float* __restrict__ gP) {
    __shared__ float Bs[64*64];

    int part = blockIdx.x & 1;
    int bt   = blockIdx.x >> 1;
    int tile = bt % 24;
    int b    = bt / 24;
    int wc0  = tile * 64;
    int tid  = threadIdx.x;
    int wave = tid >> 6;
    int lane = tid & 63;
    int n16  = lane & 15;
    int q    = lane >> 4;

    // staging coords: 16 lanes x 16B cover one 64-wc row; 16 rows per round
    int hrow = tid >> 4;   // 0..15
    int col4 = tid & 15;   // wc granule = col4 (wc = col4*4 + i)

    floatx4 acc[4];
    #pragma unroll
    for (int mt = 0; mt < 4; ++mt) acc[mt] = (floatx4){0.f, 0.f, 0.f, 0.f};

    const float*          imb = img + (size_t)b * IMG * ROWB + wc0 + col4*4;
    const unsigned short* ayb = AyT + (size_t)b * GOUT * IMG;
    int h0 = part * 256;

    floatv4 rr[4];
    #define LOADT(t) do { \
        const floatv4* p_ = (const floatv4*)(imb + (size_t)(h0 + (t)*64 + hrow) * ROWB); \
        rr[0] = p_[0]; \
        rr[1] = p_[(16*ROWB)/4]; \
        rr[2] = p_[(32*ROWB)/4]; \
        rr[3] = p_[(48*ROWB)/4]; \
    } while (0)

    LOADT(0);

    for (int t = 0; t < 4; ++t) {
        // scatter-write chunk t (swizzled): elem (wc, h=r*16+hrow) ->
        // dword wc*64 + ((hg ^ (wc>>2))<<2) + (h&3), hg = 4r + (hrow>>2)
        #pragma unroll
        for (int r = 0; r < 4; ++r) {
            int hg = 4*r + (hrow >> 2);
            int ho = hrow & 3;
            #pragma unroll
            for (int i = 0; i < 4; ++i) {
                int wc = col4*4 + i;
                Bs[wc*64 + ((hg ^ col4) << 2) + ho] = rr[r][i];
            }
        }
        __syncthreads();

        if (t < 3) LOADT(t+1);   // T14: issue next tile, hide under compute

        int hb  = h0 + t*64;
        int wc  = wave*16 + n16;
        int key = (wc >> 2);     // = wave*4 + (n16>>2)
        int wcr = wc * 64;
        #pragma unroll
        for (int s = 0; s < 2; ++s) {
            int hg0 = s*8 + q*2;
            floatv4 v0 = *(const floatv4*)&Bs[wcr + ((hg0       ^ key) << 2)];
            floatv4 v1 = *(const floatv4*)&Bs[wcr + (((hg0 + 1) ^ key) << 2)];
            short8 bf;
            bf[0] = (short)f2bf(v0[0]); bf[1] = (short)f2bf(v0[1]);
            bf[2] = (short)f2bf(v0[2]); bf[3] = (short)f2bf(v0[3]);
            bf[4] = (short)f2bf(v1[0]); bf[5] = (short)f2bf(v1[1]);
            bf[6] = (short)f2bf(v1[2]); bf[7] = (short)f2bf(v1[3]);

            int hk = hb + s*32 + q*8;
            #pragma unroll
            for (int mt = 0; mt < 4; ++mt) {
                short8 af = *(const short8*)(ayb + (size_t)(mt*16 + n16) * IMG + hk);
                acc[mt] = __builtin_amdgcn_mfma_f32_16x16x32_bf16(af, bf, acc[mt], 0, 0, 0);
            }
        }
        __syncthreads();
    }
    #undef LOADT

    // Epilogue: D col = lane&15 -> wc, row = q*4+reg -> H (verified r4/r5).
    int wcg = wc0 + wave*16 + n16;
    int c = wcg % 3, w = wcg / 3;
    float* gb = gP + (size_t)part * GP + ((size_t)(b*CH + c) * GOUT) * IMG + w;
    #pragma unroll
    for (int mt = 0; mt < 4; ++mt)
        #pragma unroll
        for (int reg = 0; reg < 4; ++reg)
            gb[(size_t)(mt*16 + q*4 + reg) * IMG] = acc[mt][reg];
}

// ---------------------------------------------------------------------------
// Kernel 3: out[b,H,W,c] += sum_{w in part} (g0+g1)[b,c,H,w] * Ax[b,w,W]
// Round-7: K(=w)-split 2 -> 768 blocks (3/CU) for occupancy; fp32 atomicAdd
// into memset output (2-way address contention only).
// ---------------------------------------------------------------------------
__global__ __launch_bounds__(256) void stage2_kernel(const float* __restrict__ gP,
                                                     const unsigned short* __restrict__ AxT,
                                                     float* __restrict__ out) {
    int blk  = blockIdx.x;
    int part = blk & 1;
    int hq   = (blk >> 1) & 3;    // H-quadrant (16 rows)
    int bc   = blk >> 3;
    int c    = bc % 3;
    int b    = bc / 3;
    int tid  = threadIdx.x;
    int wave = tid >> 6;          // owns W-tile wave*16..+15
    int lane = tid & 63;
    int n16  = lane & 15;
    int q    = lane >> 4;

    floatx4 acc = (floatx4){0.f, 0.f, 0.f, 0.f};

    const float*          ga  = gP  + ((size_t)(b*CH + c) * GOUT + hq*16 + n16) * IMG;
    const unsigned short* axb = AxT + ((size_t)b*GOUT + wave*16 + n16) * IMG;

    #pragma unroll
    for (int cc = 0; cc < 8; ++cc) {
        int w0 = part*256 + cc*32 + q*8;
        floatv4 a0 = *(const floatv4*)(ga + w0);
        floatv4 a1 = *(const floatv4*)(ga + w0 + 4);
        floatv4 b0 = *(const floatv4*)(ga + GP + w0);
        floatv4 b1 = *(const floatv4*)(ga + GP + w0 + 4);
        short8 af;
        af[0] = (short)f2bf(a0[0] + b0[0]); af[1] = (short)f2bf(a0[1] + b0[1]);
        af[2] = (short)f2bf(a0[2] + b0[2]); af[3] = (short)f2bf(a0[3] + b0[3]);
        af[4] = (short)f2bf(a1[0] + b1[0]); af[5] = (short)f2bf(a1[1] + b1[1]);
        af[6] = (short)f2bf(a1[2] + b1[2]); af[7] = (short)f2bf(a1[3] + b1[3]);

        short8 bf = *(const short8*)(axb + w0);
        acc = __builtin_amdgcn_mfma_f32_16x16x32_bf16(af, bf, acc, 0, 0, 0);
    }

    float* ob = out + (((size_t)b*GOUT + hq*16) * GOUT + wave*16 + n16) * CH + c;
    #pragma unroll
    for (int reg = 0; reg < 4; ++reg)
        atomicAdd(ob + (size_t)(q*4 + reg) * GOUT * CH, acc[reg]);
}

// ---------------------------------------------------------------------------
// Workspace: AyT 2 MB | AxT 2 MB | gP 2 x 12.6 MB  (~29 MB).
// ---------------------------------------------------------------------------
extern "C" void kernel_launch(void* const* d_in, const int* in_sizes, int n_in,
                              void* d_out, int out_size, void* d_ws, size_t ws_size,
                              hipStream_t stream) {
    const float* img = (const float*)d_in[0];
    const float* tp  = (const float*)d_in[1];
    float* out = (float*)d_out;

    unsigned short* AyT = (unsigned short*)d_ws;
    unsigned short* AxT = AyT + (size_t)BATCH * GOUT * IMG;
    float*          gPp = (float*)(AxT + (size_t)BATCH * GOUT * IMG);

    hipMemsetAsync(d_out, 0, (size_t)out_size * sizeof(float), stream);
    mask_kernel  <<<BATCH * 2 * GOUT,    64, 0, stream>>>(tp, AyT, AxT);
    stage1_kernel<<<BATCH * 24 * 2,     256, 0, stream>>>(img, AyT, gPp);
    stage2_kernel<<<BATCH * CH * 4 * 2, 256, 0, stream>>>(gPp, AxT, out);
}